// Round 12
// baseline (535.287 us; speedup 1.0000x reference)
//
#include <hip/hip_runtime.h>

// PocketGNN on MI355X — round 8.
// - EdgeConv first matmul on nodes: A = x@(w1t-w1b)+b1 (f16), B = x@w1b (f16)
// - edge_gemm: 512 thr / 8 waves, wave = M64 x N32. Wave's full w2T slice (64 VGPRs)
//   loaded once and FORCED resident via asm "+v" launder (round 7: compiler sank the
//   preload, VGPR=40). K-loop = pure ds_read+MFMA.
// - 5 tiles per block, double-buffered LDS (T14 pipeline): tile t+1 gathers issued
//   before tile t GEMM -> HBM/L2 gather latency hidden under ~3000cyc LDS+MFMA phase.
// - Edges dst-sorted; permuted LDS rows (bit-swap involution) so each lane's 16 acc
//   values are 16 consecutive sorted edges -> register segment-max, merged atomics.
// - XCD-chunked bijective block swizzle (grid 500 = 8*62+4).
// - relu(segment_max) == atomicMax(int) of positives into zero-init y.

#define NN 10000
#define NE 160000
#define NG 64
#define NP 10048  // nodes padded to 64
#define EB 64     // edges per tile
#define TPB 5     // tiles per block
#define NBLK 500  // 2500 tiles / 5

typedef __attribute__((ext_vector_type(8))) _Float16 f16x8;
typedef __attribute__((ext_vector_type(4))) _Float16 f16x4;
typedef __attribute__((ext_vector_type(4))) float f32x4;

// ---------------- edge sort by dst (counting sort) ----------------
__global__ void hist_kernel(const int* __restrict__ dstI, int* __restrict__ hist) {
    int i = blockIdx.x * blockDim.x + threadIdx.x;
    if (i < NE) atomicAdd(&hist[dstI[i]], 1);
}

// in-place safe: cursor may alias hist
__global__ void scan_kernel(const int* __restrict__ hist, int* __restrict__ cursor) {
    __shared__ int sums[256];
    const int t = threadIdx.x;
    const int per = (NN + 255) / 256;  // 40
    const int lo = t * per, hi = (lo + per < NN) ? lo + per : NN;
    int s = 0;
    for (int i = lo; i < hi; ++i) s += hist[i];
    sums[t] = s;
    __syncthreads();
    for (int ofs = 1; ofs < 256; ofs <<= 1) {
        int add = (t >= ofs) ? sums[t - ofs] : 0;
        __syncthreads();
        sums[t] += add;
        __syncthreads();
    }
    int run = sums[t] - s;  // exclusive prefix
    for (int i = lo; i < hi; ++i) {
        int h = hist[i];      // read BEFORE aliased write
        cursor[i] = run;
        run += h;
    }
}

__global__ void scatter_kernel(const int* __restrict__ srcI, const int* __restrict__ dstI,
                               int* __restrict__ cursor,
                               int* __restrict__ se2, int* __restrict__ de2) {
    int i = blockIdx.x * blockDim.x + threadIdx.x;
    if (i < NE) {
        int d = dstI[i];
        int p = atomicAdd(&cursor[d], 1);
        se2[p] = srcI[i];
        de2[p] = d;
    }
}

// ---------------- weight prep ----------------
// WcT [512][C]: rows 0..255 = (w1t-w1b)^T, 256..511 = w1b^T.  w2T [256][256] = w2^T.
__global__ void prep_weights(const float* __restrict__ w1, const float* __restrict__ w2, int C,
                             _Float16* __restrict__ WcT, _Float16* __restrict__ w2T) {
    int total1 = 512 * C;
    int total = total1 + 256 * 256;
    for (int i = blockIdx.x * blockDim.x + threadIdx.x; i < total; i += gridDim.x * blockDim.x) {
        if (i < total1) {
            int n = i / C, k = i - n * C;
            float v = (n < 256) ? (w1[k * 256 + n] - w1[(C + k) * 256 + n])
                                : w1[(C + k) * 256 + (n - 256)];
            WcT[n * C + k] = (_Float16)v;
        } else {
            int j = i - total1;
            int n = j >> 8, k = j & 255;
            w2T[n * 256 + k] = (_Float16)w2[k * 256 + n];
        }
    }
}

// ---------------- node GEMM: [A | B] = x @ [Wc_A | Wc_B]; both f16 (A gets +b1) --------
// grid (157,4): wave = M64 x N32 -> 628 blocks, ~10 waves/CU for latency hiding.
// Reads f32 activations directly (x0 or y), converts inline; rows clamped (pad never used).
template <int C>
__global__ __launch_bounds__(256, 4) void node_gemm(
    const float* __restrict__ xf, const _Float16* __restrict__ WT,
    const float* __restrict__ b1, _Float16* __restrict__ Afh, _Float16* __restrict__ Bh) {
    const int wave = threadIdx.x >> 6, lane = threadIdx.x & 63;
    const int lrow = lane & 15, lk = (lane >> 4) * 8;
    const int r0 = blockIdx.x * 64;
    const int c0 = blockIdx.y * 128 + wave * 32;

    f32x4 acc[4][2] = {};
#pragma unroll
    for (int kk = 0; kk < C; kk += 32) {
        f16x8 ah[4];
#pragma unroll
        for (int m = 0; m < 4; ++m) {
            int rc = r0 + m * 16 + lrow;
            if (rc > NN - 1) rc = NN - 1;
            const float* xp = xf + (size_t)rc * C + kk + lk;
            const float4 v0 = *(const float4*)(xp);
            const float4 v1 = *(const float4*)(xp + 4);
            f16x8 a;
            a[0] = (_Float16)v0.x; a[1] = (_Float16)v0.y;
            a[2] = (_Float16)v0.z; a[3] = (_Float16)v0.w;
            a[4] = (_Float16)v1.x; a[5] = (_Float16)v1.y;
            a[6] = (_Float16)v1.z; a[7] = (_Float16)v1.w;
            ah[m] = a;
        }
#pragma unroll
        for (int t = 0; t < 2; ++t) {
            f16x8 bh = *(const f16x8*)(WT + (size_t)(c0 + t * 16 + lrow) * C + kk + lk);
#pragma unroll
            for (int m = 0; m < 4; ++m)
                acc[m][t] = __builtin_amdgcn_mfma_f32_16x16x32_f16(ah[m], bh, acc[m][t], 0, 0, 0);
        }
    }
    if (blockIdx.y < 2) {  // A half: +bias (f32), store f16
#pragma unroll
        for (int t = 0; t < 2; ++t) {
            const int col = c0 + t * 16 + lrow;
            const float bias = b1[col];
#pragma unroll
            for (int m = 0; m < 4; ++m)
#pragma unroll
                for (int j = 0; j < 4; ++j) {
                    const int row = r0 + m * 16 + (lane >> 4) * 4 + j;
                    Afh[(size_t)row * 256 + col] = (_Float16)(acc[m][t][j] + bias);
                }
        }
    } else {  // B half: f16
#pragma unroll
        for (int t = 0; t < 2; ++t) {
            const int col = c0 - 256 + t * 16 + lrow;
#pragma unroll
            for (int m = 0; m < 4; ++m)
#pragma unroll
                for (int j = 0; j < 4; ++j) {
                    const int row = r0 + m * 16 + (lane >> 4) * 4 + j;
                    Bh[(size_t)row * 256 + col] = (_Float16)acc[m][t][j];
                }
        }
    }
}

// ---------------- fused edge kernel: 5-tile pipeline, resident w2T ----------------
__global__ __launch_bounds__(512, 3) void edge_gemm(
    const _Float16* __restrict__ Afh, const _Float16* __restrict__ Bh,
    const int* __restrict__ se2, const int* __restrict__ de2,
    const _Float16* __restrict__ w2T,
    const float* __restrict__ b2, float* __restrict__ y) {
    __shared__ _Float16 hh[2 * EB * 256];  // 64 KB double buffer, XOR-swizzled
    const int tid = threadIdx.x;
    const int wave = tid >> 6, lane = tid & 63;
    const int lrow = lane & 15, lk = (lane >> 4) * 8;

    // XCD-chunked bijective swizzle over 500 blocks (= 8*62 + 4)
    const int orig = blockIdx.x;
    const int xcd = orig & 7, pos = orig >> 3;
    const int qq = NBLK >> 3, rr = NBLK & 7;  // 62, 4
    const int bid = (xcd < rr ? xcd * (qq + 1) : rr * (qq + 1) + (xcd - rr) * qq) + pos;
    const int t0 = bid * TPB;  // first tile

    // ---- resident w2T slice: wave cols [wave*32, wave*32+32), full K=256 ----
    f16x8 w[16];  // w[q]: t-tile 0, kk=q*32 ; w[8+q]: t-tile 1
    const _Float16* wbase = w2T + (size_t)(wave * 32 + lrow) * 256 + lk;
#pragma unroll
    for (int q = 0; q < 8; ++q) {
        w[q]     = *(const f16x8*)(wbase + q * 32);
        w[8 + q] = *(const f16x8*)(wbase + 16 * 256 + q * 32);
    }

    f16x4 av[8], bv[8];
    int se[8], de[8];

    auto stage_issue = [&](int tile) {
#pragma unroll
        for (int i = 0; i < 8; ++i) {
            const int e = tile * EB + wave * 8 + i;
            se[i] = se2[e];
            de[i] = de2[e];
        }
#pragma unroll
        for (int i = 0; i < 8; ++i) {
            bv[i] = *(const f16x4*)(Bh + (size_t)se[i] * 256 + lane * 4);
            av[i] = *(const f16x4*)(Afh + (size_t)de[i] * 256 + lane * 4);
        }
    };
    auto stage_write = [&](int buf) {
#pragma unroll
        for (int i = 0; i < 8; ++i) {
            const int el = wave * 8 + i;  // block-local edge 0..63
            const int row = ((el >> 2) & 3) * 16 + (el >> 4) * 4 + (el & 3);
            f16x4 h = av[i] + bv[i];
#pragma unroll
            for (int k = 0; k < 4; ++k) h[k] = h[k] > (_Float16)0.f ? h[k] : (_Float16)0.f;
            *(f16x4*)(&hh[buf * (EB * 256) + ((row * 256 + lane * 4) ^ ((row & 7) << 3))]) = h;
        }
    };

    // prologue: stage tile 0 into buf 0
    stage_issue(t0);
    stage_write(0);
    __syncthreads();  // implicit vmcnt(0) also drains the w loads

    // launder w so the compiler cannot sink/rematerialize the loads into the K-loop
#pragma unroll
    for (int q = 0; q < 16; ++q) {
        f32x4 tmp = __builtin_bit_cast(f32x4, w[q]);
        asm volatile("" : "+v"(tmp));
        w[q] = __builtin_bit_cast(f16x8, tmp);
    }

    for (int tt = 0; tt < TPB; ++tt) {
        const int tile = t0 + tt;
        const int hbase = (tt & 1) * (EB * 256);

        if (tt + 1 < TPB) stage_issue(tile + 1);  // overlap next gather with GEMM

        // ---- GEMM: M=64 (4 tiles) x N=32 (2 tiles), K=256; pure LDS+MFMA ----
        f32x4 acc[4][2] = {};
#pragma unroll
        for (int q = 0; q < 8; ++q) {
            f16x8 ah[4];
#pragma unroll
            for (int m = 0; m < 4; ++m) {
                const int row = m * 16 + lrow;
                const int idx = (row * 256 + q * 32 + lk) ^ ((row & 7) << 3);
                ah[m] = *(const f16x8*)(&hh[hbase + idx]);
            }
#pragma unroll
            for (int m = 0; m < 4; ++m) {
                acc[m][0] = __builtin_amdgcn_mfma_f32_16x16x32_f16(ah[m], w[q],     acc[m][0], 0, 0, 0);
                acc[m][1] = __builtin_amdgcn_mfma_f32_16x16x32_f16(ah[m], w[8 + q], acc[m][1], 0, 0, 0);
            }
        }

        // ---- epilogue: lane quarter g holds edges tile*64 + g*16..+15 (consecutive) ----
        {
            const int g = lane >> 4;
            const int e0 = tile * EB;
            int d[16];
#pragma unroll
            for (int k = 0; k < 16; ++k) d[k] = de2[e0 + g * 16 + k];
#pragma unroll
            for (int t = 0; t < 2; ++t) {
                const int col = wave * 32 + t * 16 + lrow;
                const float bias = b2[col];  // constant per col: apply AFTER segment max
                float run = acc[0][t][0];
                int dp = d[0];
#pragma unroll
                for (int k = 1; k < 16; ++k) {
                    const float v = acc[k >> 2][t][k & 3];
                    if (d[k] == dp) {
                        run = fmaxf(run, v);
                    } else {
                        const float o = run + bias;
                        if (o > 0.f) atomicMax((int*)(y + (size_t)dp * 256 + col), __float_as_int(o));
                        run = v;
                        dp = d[k];
                    }
                }
                const float o = run + bias;
                if (o > 0.f) atomicMax((int*)(y + (size_t)dp * 256 + col), __float_as_int(o));
            }
        }

        if (tt + 1 < TPB) stage_write((tt + 1) & 1);
        __syncthreads();
    }
}

// ---------------- per-graph mean+max pool (4 row-slices per block) ----------------
__global__ void pool_kernel(const float* __restrict__ y, const int* __restrict__ batch,
                            float* __restrict__ pooled) {
    const int g = blockIdx.x;
    __shared__ int slo, shi;
    __shared__ float ssum[4][256];
    __shared__ float smax[4][256];
    const int c = threadIdx.x, ry = threadIdx.y;
    if (c == 0 && ry == 0) {
        int lo = 0, hi = NN;
        while (lo < hi) { int m = (lo + hi) >> 1; if (batch[m] < g) lo = m + 1; else hi = m; }
        slo = lo;
        int lo2 = lo, hi2 = NN;
        while (lo2 < hi2) { int m = (lo2 + hi2) >> 1; if (batch[m] < g + 1) lo2 = m + 1; else hi2 = m; }
        shi = lo2;
    }
    __syncthreads();
    const int lo = slo, hi = shi;
    float s = 0.f, mx = 0.f;  // y >= 0 -> 0 safe identity
    for (int n = lo + ry; n < hi; n += 4) {
        const float v = y[(size_t)n * 256 + c];
        s += v;
        mx = fmaxf(mx, v);
    }
    ssum[ry][c] = s;
    smax[ry][c] = mx;
    __syncthreads();
    if (ry == 0) {
        const float st = (ssum[0][c] + ssum[1][c]) + (ssum[2][c] + ssum[3][c]);
        const float mt = fmaxf(fmaxf(smax[0][c], smax[1][c]), fmaxf(smax[2][c], smax[3][c]));
        const int cnt = hi - lo;
        pooled[g * 512 + c] = cnt ? st / (float)cnt : 0.f;
        pooled[g * 512 + 256 + c] = cnt ? mt : 0.f;
    }
}

// ---------------- classifier MLP ----------------
__global__ void classifier(const float* __restrict__ pooled,
                           const float* __restrict__ w1, const float* __restrict__ b1,
                           const float* __restrict__ w2, const float* __restrict__ b2,
                           const float* __restrict__ w3, const float* __restrict__ b3,
                           float* __restrict__ out) {
    const int g = blockIdx.x;
    __shared__ float ph[512];
    __shared__ float o1[256];
    __shared__ float o2[64];
    const int t = threadIdx.x;  // 256 threads
    ph[t] = pooled[g * 512 + t];
    ph[t + 256] = pooled[g * 512 + 256 + t];
    __syncthreads();
    float s = 0.f;
    for (int k = 0; k < 512; ++k) s += ph[k] * w1[k * 256 + t];
    o1[t] = fmaxf(s + b1[t], 0.f);
    __syncthreads();
    if (t < 64) {
        float s2 = 0.f;
        for (int k = 0; k < 256; ++k) s2 += o1[k] * w2[k * 64 + t];
        o2[t] = fmaxf(s2 + b2[t], 0.f);
    }
    __syncthreads();
    if (t < 64) {
        float v = o2[t] * w3[t];
        for (int off = 32; off; off >>= 1) v += __shfl_down(v, off);
        if (t == 0) out[g] = v + b3[0];
    }
}

extern "C" void kernel_launch(void* const* d_in, const int* in_sizes, int n_in,
                              void* d_out, int out_size, void* d_ws, size_t ws_size,
                              hipStream_t stream) {
    (void)in_sizes; (void)n_in; (void)out_size; (void)ws_size;
    const float* x0 = (const float*)d_in[0];
    const int* eidx = (const int*)d_in[1];
    const int* batch = (const int*)d_in[2];
    const int* srcI = eidx;            // edge_index[0] = src
    const int* dstI = eidx + NE;       // edge_index[1] = dst

    char* ws = (char*)d_ws;
    size_t off = 0;
    auto alloc = [&](size_t bytes) -> void* {
        void* p = ws + off;
        off += (bytes + 255) & ~(size_t)255;
        return p;
    };
    _Float16* Afh = (_Float16*)alloc((size_t)NP * 256 * 2);
    _Float16* Bh  = (_Float16*)alloc((size_t)NP * 256 * 2);
    float* y  = (float*)alloc((size_t)NP * 256 * 4);
    _Float16* WcT = (_Float16*)alloc(512 * 256 * 2);
    _Float16* w2T = (_Float16*)alloc(256 * 256 * 2);
    float* pooled = (float*)alloc(64 * 512 * 4);
    int* hist = (int*)alloc(NN * 4);
    int* se2 = (int*)alloc(NE * 4);
    int* de2 = (int*)alloc(NE * 4);

    const float* lw[3][4] = {
        {(const float*)d_in[3],  (const float*)d_in[4],  (const float*)d_in[5],  (const float*)d_in[6]},
        {(const float*)d_in[7],  (const float*)d_in[8],  (const float*)d_in[9],  (const float*)d_in[10]},
        {(const float*)d_in[11], (const float*)d_in[12], (const float*)d_in[13], (const float*)d_in[14]},
    };

    // sort edges by dst (once, reused all layers)
    hipMemsetAsync(hist, 0, NN * 4, stream);
    hist_kernel<<<dim3((NE + 255) / 256), dim3(256), 0, stream>>>(dstI, hist);
    scan_kernel<<<dim3(1), dim3(256), 0, stream>>>(hist, hist);  // in-place exclusive scan
    scatter_kernel<<<dim3((NE + 255) / 256), dim3(256), 0, stream>>>(srcI, dstI, hist, se2, de2);

    for (int l = 0; l < 3; ++l) {
        const int C = (l == 0) ? 128 : 256;
        prep_weights<<<dim3(256), dim3(256), 0, stream>>>(lw[l][0], lw[l][2], C, WcT, w2T);
        if (C == 128)
            node_gemm<128><<<dim3(NP / 64, 4), dim3(256), 0, stream>>>(x0, WcT, lw[l][1], Afh, Bh);
        else
            node_gemm<256><<<dim3(NP / 64, 4), dim3(256), 0, stream>>>(y, WcT, lw[l][1], Afh, Bh);
        hipMemsetAsync(y, 0, (size_t)NP * 256 * 4, stream);
        edge_gemm<<<dim3(NBLK), dim3(512), 0, stream>>>(Afh, Bh, se2, de2, w2T, lw[l][3], y);
    }

    pool_kernel<<<dim3(NG), dim3(256, 4), 0, stream>>>(y, batch, pooled);
    classifier<<<dim3(NG), dim3(256), 0, stream>>>(pooled,
        (const float*)d_in[15], (const float*)d_in[16],
        (const float*)d_in[17], (const float*)d_in[18],
        (const float*)d_in[19], (const float*)d_in[20], (float*)d_out);
}

// Round 13
// 474.627 us; speedup vs baseline: 1.1278x; 1.1278x over previous
//
#include <hip/hip_runtime.h>

// PocketGNN on MI355X — round 9.
// - EdgeConv first matmul on nodes: A = x@(w1t-w1b)+b1 (f16), B = x@w1b (f16)
// - edge_gemm: 512 thr / 8 waves, wave = M64 x N32, EB=64, 5 tiles/block with
//   double-buffered LDS: tile t+1's gathers are issued BEFORE tile t's GEMM, so
//   gather latency hides under ~2000cyc of LDS+MFMA+epilogue. ONE barrier per tile.
//   R8's regression was register spill (resident w2T blew 128 regs -> scratch, WRITE
//   +37MB); R9 drops resident-w (bh streams from L2 per kk, as in the 66us R5-R7
//   kernels) so the live set is ~110 regs and (512,4) holds 2 blocks/CU.
// - Edges dst-sorted; permuted LDS rows (bit-swap involution) so each lane's 16 acc
//   values are 16 consecutive sorted edges -> register segment-max, merged atomics.
// - XCD-chunked bijective block swizzle (grid 500 = 8*62+4).
// - relu(segment_max) == atomicMax(int) of positives into zero-init y.

#define NN 10000
#define NE 160000
#define NG 64
#define NP 10048  // nodes padded to 64
#define EB 64     // edges per tile
#define TPB 5     // tiles per block
#define NBLK 500  // 2500 tiles / 5

typedef __attribute__((ext_vector_type(8))) _Float16 f16x8;
typedef __attribute__((ext_vector_type(4))) _Float16 f16x4;
typedef __attribute__((ext_vector_type(4))) float f32x4;

// ---------------- edge sort by dst (counting sort) ----------------
__global__ void hist_kernel(const int* __restrict__ dstI, int* __restrict__ hist) {
    int i = blockIdx.x * blockDim.x + threadIdx.x;
    if (i < NE) atomicAdd(&hist[dstI[i]], 1);
}

// in-place safe: cursor may alias hist
__global__ void scan_kernel(const int* __restrict__ hist, int* __restrict__ cursor) {
    __shared__ int sums[256];
    const int t = threadIdx.x;
    const int per = (NN + 255) / 256;  // 40
    const int lo = t * per, hi = (lo + per < NN) ? lo + per : NN;
    int s = 0;
    for (int i = lo; i < hi; ++i) s += hist[i];
    sums[t] = s;
    __syncthreads();
    for (int ofs = 1; ofs < 256; ofs <<= 1) {
        int add = (t >= ofs) ? sums[t - ofs] : 0;
        __syncthreads();
        sums[t] += add;
        __syncthreads();
    }
    int run = sums[t] - s;  // exclusive prefix
    for (int i = lo; i < hi; ++i) {
        int h = hist[i];      // read BEFORE aliased write
        cursor[i] = run;
        run += h;
    }
}

__global__ void scatter_kernel(const int* __restrict__ srcI, const int* __restrict__ dstI,
                               int* __restrict__ cursor,
                               int* __restrict__ se2, int* __restrict__ de2) {
    int i = blockIdx.x * blockDim.x + threadIdx.x;
    if (i < NE) {
        int d = dstI[i];
        int p = atomicAdd(&cursor[d], 1);
        se2[p] = srcI[i];
        de2[p] = d;
    }
}

// ---------------- weight prep ----------------
// WcT [512][C]: rows 0..255 = (w1t-w1b)^T, 256..511 = w1b^T.  w2T [256][256] = w2^T.
__global__ void prep_weights(const float* __restrict__ w1, const float* __restrict__ w2, int C,
                             _Float16* __restrict__ WcT, _Float16* __restrict__ w2T) {
    int total1 = 512 * C;
    int total = total1 + 256 * 256;
    for (int i = blockIdx.x * blockDim.x + threadIdx.x; i < total; i += gridDim.x * blockDim.x) {
        if (i < total1) {
            int n = i / C, k = i - n * C;
            float v = (n < 256) ? (w1[k * 256 + n] - w1[(C + k) * 256 + n])
                                : w1[(C + k) * 256 + (n - 256)];
            WcT[n * C + k] = (_Float16)v;
        } else {
            int j = i - total1;
            int n = j >> 8, k = j & 255;
            w2T[n * 256 + k] = (_Float16)w2[k * 256 + n];
        }
    }
}

// ---------------- node GEMM: [A | B] = x @ [Wc_A | Wc_B]; both f16 (A gets +b1) --------
// grid (157,4): wave = M64 x N32 -> 628 blocks, ~10 waves/CU for latency hiding.
// Reads f32 activations directly (x0 or y), converts inline; rows clamped (pad never used).
template <int C>
__global__ __launch_bounds__(256, 4) void node_gemm(
    const float* __restrict__ xf, const _Float16* __restrict__ WT,
    const float* __restrict__ b1, _Float16* __restrict__ Afh, _Float16* __restrict__ Bh) {
    const int wave = threadIdx.x >> 6, lane = threadIdx.x & 63;
    const int lrow = lane & 15, lk = (lane >> 4) * 8;
    const int r0 = blockIdx.x * 64;
    const int c0 = blockIdx.y * 128 + wave * 32;

    f32x4 acc[4][2] = {};
#pragma unroll
    for (int kk = 0; kk < C; kk += 32) {
        f16x8 ah[4];
#pragma unroll
        for (int m = 0; m < 4; ++m) {
            int rc = r0 + m * 16 + lrow;
            if (rc > NN - 1) rc = NN - 1;
            const float* xp = xf + (size_t)rc * C + kk + lk;
            const float4 v0 = *(const float4*)(xp);
            const float4 v1 = *(const float4*)(xp + 4);
            f16x8 a;
            a[0] = (_Float16)v0.x; a[1] = (_Float16)v0.y;
            a[2] = (_Float16)v0.z; a[3] = (_Float16)v0.w;
            a[4] = (_Float16)v1.x; a[5] = (_Float16)v1.y;
            a[6] = (_Float16)v1.z; a[7] = (_Float16)v1.w;
            ah[m] = a;
        }
#pragma unroll
        for (int t = 0; t < 2; ++t) {
            f16x8 bh = *(const f16x8*)(WT + (size_t)(c0 + t * 16 + lrow) * C + kk + lk);
#pragma unroll
            for (int m = 0; m < 4; ++m)
                acc[m][t] = __builtin_amdgcn_mfma_f32_16x16x32_f16(ah[m], bh, acc[m][t], 0, 0, 0);
        }
    }
    if (blockIdx.y < 2) {  // A half: +bias (f32), store f16
#pragma unroll
        for (int t = 0; t < 2; ++t) {
            const int col = c0 + t * 16 + lrow;
            const float bias = b1[col];
#pragma unroll
            for (int m = 0; m < 4; ++m)
#pragma unroll
                for (int j = 0; j < 4; ++j) {
                    const int row = r0 + m * 16 + (lane >> 4) * 4 + j;
                    Afh[(size_t)row * 256 + col] = (_Float16)(acc[m][t][j] + bias);
                }
        }
    } else {  // B half: f16
#pragma unroll
        for (int t = 0; t < 2; ++t) {
            const int col = c0 - 256 + t * 16 + lrow;
#pragma unroll
            for (int m = 0; m < 4; ++m)
#pragma unroll
                for (int j = 0; j < 4; ++j) {
                    const int row = r0 + m * 16 + (lane >> 4) * 4 + j;
                    Bh[(size_t)row * 256 + col] = (_Float16)acc[m][t][j];
                }
        }
    }
}

// ---------------- fused edge kernel: 5-tile pipeline, bh streamed from L2 ----------------
__global__ __launch_bounds__(512, 4) void edge_gemm(
    const _Float16* __restrict__ Afh, const _Float16* __restrict__ Bh,
    const int* __restrict__ se2, const int* __restrict__ de2,
    const _Float16* __restrict__ w2T,
    const float* __restrict__ b2, float* __restrict__ y) {
    __shared__ _Float16 hh[2 * EB * 256];  // 64 KB double buffer, XOR-swizzled
    const int tid = threadIdx.x;
    const int wave = tid >> 6, lane = tid & 63;
    const int lrow = lane & 15, lk = (lane >> 4) * 8;

    // XCD-chunked bijective swizzle over 500 blocks (= 8*62 + 4)
    const int orig = blockIdx.x;
    const int xcd = orig & 7, pos = orig >> 3;
    const int qq = NBLK >> 3, rr = NBLK & 7;  // 62, 4
    const int bid = (xcd < rr ? xcd * (qq + 1) : rr * (qq + 1) + (xcd - rr) * qq) + pos;
    const int t0 = bid * TPB;  // first tile

    const _Float16* wbase = w2T + (size_t)(wave * 32 + lrow) * 256 + lk;

    f16x4 av[8], bv[8];

    auto stage_issue = [&](int tile) {
        int se[8], de[8];
#pragma unroll
        for (int i = 0; i < 8; ++i) {
            const int e = tile * EB + wave * 8 + i;
            se[i] = se2[e];
            de[i] = de2[e];
        }
#pragma unroll
        for (int i = 0; i < 8; ++i) {
            bv[i] = *(const f16x4*)(Bh + (size_t)se[i] * 256 + lane * 4);
            av[i] = *(const f16x4*)(Afh + (size_t)de[i] * 256 + lane * 4);
        }
    };
    auto stage_write = [&](int buf) {
#pragma unroll
        for (int i = 0; i < 8; ++i) {
            const int el = wave * 8 + i;  // block-local edge 0..63
            const int row = ((el >> 2) & 3) * 16 + (el >> 4) * 4 + (el & 3);
            f16x4 h = av[i] + bv[i];
#pragma unroll
            for (int k = 0; k < 4; ++k) h[k] = h[k] > (_Float16)0.f ? h[k] : (_Float16)0.f;
            *(f16x4*)(&hh[buf * (EB * 256) + ((row * 256 + lane * 4) ^ ((row & 7) << 3))]) = h;
        }
    };

    // prologue: stage tile 0 into buf 0
    stage_issue(t0);
    stage_write(0);
    __syncthreads();

    for (int tt = 0; tt < TPB; ++tt) {
        const int tile = t0 + tt;
        const int hbase = (tt & 1) * (EB * 256);

        if (tt + 1 < TPB) stage_issue(tile + 1);  // gathers fly during GEMM+epilogue

        // ---- GEMM: M=64 (4 tiles) x N=32 (2 tiles), K=256; bh streams from L2 ----
        f32x4 acc[4][2] = {};
#pragma unroll
        for (int q = 0; q < 8; ++q) {
            f16x8 bh0 = *(const f16x8*)(wbase + q * 32);
            f16x8 bh1 = *(const f16x8*)(wbase + 16 * 256 + q * 32);
            f16x8 ah[4];
#pragma unroll
            for (int m = 0; m < 4; ++m) {
                const int row = m * 16 + lrow;
                const int idx = (row * 256 + q * 32 + lk) ^ ((row & 7) << 3);
                ah[m] = *(const f16x8*)(&hh[hbase + idx]);
            }
#pragma unroll
            for (int m = 0; m < 4; ++m) {
                acc[m][0] = __builtin_amdgcn_mfma_f32_16x16x32_f16(ah[m], bh0, acc[m][0], 0, 0, 0);
                acc[m][1] = __builtin_amdgcn_mfma_f32_16x16x32_f16(ah[m], bh1, acc[m][1], 0, 0, 0);
            }
        }

        // ---- epilogue: lane quarter g holds edges tile*64 + g*16..+15 (consecutive) ----
        {
            const int g = lane >> 4;
            const int e0 = tile * EB;
            int d[16];
#pragma unroll
            for (int k = 0; k < 16; ++k) d[k] = de2[e0 + g * 16 + k];
#pragma unroll
            for (int t = 0; t < 2; ++t) {
                const int col = wave * 32 + t * 16 + lrow;
                const float bias = b2[col];  // constant per col: apply AFTER segment max
                float run = acc[0][t][0];
                int dp = d[0];
#pragma unroll
                for (int k = 1; k < 16; ++k) {
                    const float v = acc[k >> 2][t][k & 3];
                    if (d[k] == dp) {
                        run = fmaxf(run, v);
                    } else {
                        const float o = run + bias;
                        if (o > 0.f) atomicMax((int*)(y + (size_t)dp * 256 + col), __float_as_int(o));
                        run = v;
                        dp = d[k];
                    }
                }
                const float o = run + bias;
                if (o > 0.f) atomicMax((int*)(y + (size_t)dp * 256 + col), __float_as_int(o));
            }
        }

        if (tt + 1 < TPB) stage_write((tt + 1) & 1);
        __syncthreads();
    }
}

// ---------------- per-graph mean+max pool (4 row-slices per block) ----------------
__global__ void pool_kernel(const float* __restrict__ y, const int* __restrict__ batch,
                            float* __restrict__ pooled) {
    const int g = blockIdx.x;
    __shared__ int slo, shi;
    __shared__ float ssum[4][256];
    __shared__ float smax[4][256];
    const int c = threadIdx.x, ry = threadIdx.y;
    if (c == 0 && ry == 0) {
        int lo = 0, hi = NN;
        while (lo < hi) { int m = (lo + hi) >> 1; if (batch[m] < g) lo = m + 1; else hi = m; }
        slo = lo;
        int lo2 = lo, hi2 = NN;
        while (lo2 < hi2) { int m = (lo2 + hi2) >> 1; if (batch[m] < g + 1) lo2 = m + 1; else hi2 = m; }
        shi = lo2;
    }
    __syncthreads();
    const int lo = slo, hi = shi;
    float s = 0.f, mx = 0.f;  // y >= 0 -> 0 safe identity
    for (int n = lo + ry; n < hi; n += 4) {
        const float v = y[(size_t)n * 256 + c];
        s += v;
        mx = fmaxf(mx, v);
    }
    ssum[ry][c] = s;
    smax[ry][c] = mx;
    __syncthreads();
    if (ry == 0) {
        const float st = (ssum[0][c] + ssum[1][c]) + (ssum[2][c] + ssum[3][c]);
        const float mt = fmaxf(fmaxf(smax[0][c], smax[1][c]), fmaxf(smax[2][c], smax[3][c]));
        const int cnt = hi - lo;
        pooled[g * 512 + c] = cnt ? st / (float)cnt : 0.f;
        pooled[g * 512 + 256 + c] = cnt ? mt : 0.f;
    }
}

// ---------------- classifier MLP ----------------
__global__ void classifier(const float* __restrict__ pooled,
                           const float* __restrict__ w1, const float* __restrict__ b1,
                           const float* __restrict__ w2, const float* __restrict__ b2,
                           const float* __restrict__ w3, const float* __restrict__ b3,
                           float* __restrict__ out) {
    const int g = blockIdx.x;
    __shared__ float ph[512];
    __shared__ float o1[256];
    __shared__ float o2[64];
    const int t = threadIdx.x;  // 256 threads
    ph[t] = pooled[g * 512 + t];
    ph[t + 256] = pooled[g * 512 + 256 + t];
    __syncthreads();
    float s = 0.f;
    for (int k = 0; k < 512; ++k) s += ph[k] * w1[k * 256 + t];
    o1[t] = fmaxf(s + b1[t], 0.f);
    __syncthreads();
    if (t < 64) {
        float s2 = 0.f;
        for (int k = 0; k < 256; ++k) s2 += o1[k] * w2[k * 64 + t];
        o2[t] = fmaxf(s2 + b2[t], 0.f);
    }
    __syncthreads();
    if (t < 64) {
        float v = o2[t] * w3[t];
        for (int off = 32; off; off >>= 1) v += __shfl_down(v, off);
        if (t == 0) out[g] = v + b3[0];
    }
}

extern "C" void kernel_launch(void* const* d_in, const int* in_sizes, int n_in,
                              void* d_out, int out_size, void* d_ws, size_t ws_size,
                              hipStream_t stream) {
    (void)in_sizes; (void)n_in; (void)out_size; (void)ws_size;
    const float* x0 = (const float*)d_in[0];
    const int* eidx = (const int*)d_in[1];
    const int* batch = (const int*)d_in[2];
    const int* srcI = eidx;            // edge_index[0] = src
    const int* dstI = eidx + NE;       // edge_index[1] = dst

    char* ws = (char*)d_ws;
    size_t off = 0;
    auto alloc = [&](size_t bytes) -> void* {
        void* p = ws + off;
        off += (bytes + 255) & ~(size_t)255;
        return p;
    };
    _Float16* Afh = (_Float16*)alloc((size_t)NP * 256 * 2);
    _Float16* Bh  = (_Float16*)alloc((size_t)NP * 256 * 2);
    float* y  = (float*)alloc((size_t)NP * 256 * 4);
    _Float16* WcT = (_Float16*)alloc(512 * 256 * 2);
    _Float16* w2T = (_Float16*)alloc(256 * 256 * 2);
    float* pooled = (float*)alloc(64 * 512 * 4);
    int* hist = (int*)alloc(NN * 4);
    int* se2 = (int*)alloc(NE * 4);
    int* de2 = (int*)alloc(NE * 4);

    const float* lw[3][4] = {
        {(const float*)d_in[3],  (const float*)d_in[4],  (const float*)d_in[5],  (const float*)d_in[6]},
        {(const float*)d_in[7],  (const float*)d_in[8],  (const float*)d_in[9],  (const float*)d_in[10]},
        {(const float*)d_in[11], (const float*)d_in[12], (const float*)d_in[13], (const float*)d_in[14]},
    };

    // sort edges by dst (once, reused all layers)
    hipMemsetAsync(hist, 0, NN * 4, stream);
    hist_kernel<<<dim3((NE + 255) / 256), dim3(256), 0, stream>>>(dstI, hist);
    scan_kernel<<<dim3(1), dim3(256), 0, stream>>>(hist, hist);  // in-place exclusive scan
    scatter_kernel<<<dim3((NE + 255) / 256), dim3(256), 0, stream>>>(srcI, dstI, hist, se2, de2);

    for (int l = 0; l < 3; ++l) {
        const int C = (l == 0) ? 128 : 256;
        prep_weights<<<dim3(256), dim3(256), 0, stream>>>(lw[l][0], lw[l][2], C, WcT, w2T);
        if (C == 128)
            node_gemm<128><<<dim3(NP / 64, 4), dim3(256), 0, stream>>>(x0, WcT, lw[l][1], Afh, Bh);
        else
            node_gemm<256><<<dim3(NP / 64, 4), dim3(256), 0, stream>>>(y, WcT, lw[l][1], Afh, Bh);
        hipMemsetAsync(y, 0, (size_t)NP * 256 * 4, stream);
        edge_gemm<<<dim3(NBLK), dim3(512), 0, stream>>>(Afh, Bh, se2, de2, w2T, lw[l][3], y);
    }

    pool_kernel<<<dim3(NG), dim3(256, 4), 0, stream>>>(y, batch, pooled);
    classifier<<<dim3(NG), dim3(256), 0, stream>>>(pooled,
        (const float*)d_in[15], (const float*)d_in[16],
        (const float*)d_in[17], (const float*)d_in[18],
        (const float*)d_in[19], (const float*)d_in[20], (float*)d_out);
}

// Round 14
// 367.191 us; speedup vs baseline: 1.4578x; 1.2926x over previous
//
#include <hip/hip_runtime.h>

// PocketGNN on MI355X — round 10.
// LESSON (R8/R9): __launch_bounds__ 2nd arg = min BLOCKS per CU (CUDA semantics).
//   (512,4) capped VGPR at 64 -> av/bv+acc spilled to scratch -> FETCH 211MB, 99us.
//   (512,2) gives the intended 2 blocks/CU (also the 64KB-LDS limit) and 128 VGPRs.
// - EdgeConv first matmul on nodes: A = x@(w1t-w1b)+b1 (f16), B = x@w1b (f16)
// - edge_gemm: 512 thr / 8 waves, wave = M64 x N32, EB=64, 5 tiles/block with
//   double-buffered LDS: tile t+1's 16 gathers issued BEFORE tile t's GEMM
//   (~2000cyc LDS+MFMA+epilogue cover). ONE barrier per tile. bh streams from L2.
// - Edges dst-sorted; permuted LDS rows (bit-swap involution) so each lane's 16 acc
//   values are 16 consecutive sorted edges -> register segment-max, merged atomics.
// - XCD-chunked bijective block swizzle (grid 500 = 8*62+4).
// - relu(segment_max) == atomicMax(int) of positives into zero-init y.

#define NN 10000
#define NE 160000
#define NG 64
#define NP 10048  // nodes padded to 64
#define EB 64     // edges per tile
#define TPB 5     // tiles per block
#define NBLK 500  // 2500 tiles / 5

typedef __attribute__((ext_vector_type(8))) _Float16 f16x8;
typedef __attribute__((ext_vector_type(4))) _Float16 f16x4;
typedef __attribute__((ext_vector_type(4))) float f32x4;

// ---------------- edge sort by dst (counting sort) ----------------
__global__ void hist_kernel(const int* __restrict__ dstI, int* __restrict__ hist) {
    int i = blockIdx.x * blockDim.x + threadIdx.x;
    if (i < NE) atomicAdd(&hist[dstI[i]], 1);
}

// in-place safe: cursor may alias hist
__global__ void scan_kernel(const int* __restrict__ hist, int* __restrict__ cursor) {
    __shared__ int sums[256];
    const int t = threadIdx.x;
    const int per = (NN + 255) / 256;  // 40
    const int lo = t * per, hi = (lo + per < NN) ? lo + per : NN;
    int s = 0;
    for (int i = lo; i < hi; ++i) s += hist[i];
    sums[t] = s;
    __syncthreads();
    for (int ofs = 1; ofs < 256; ofs <<= 1) {
        int add = (t >= ofs) ? sums[t - ofs] : 0;
        __syncthreads();
        sums[t] += add;
        __syncthreads();
    }
    int run = sums[t] - s;  // exclusive prefix
    for (int i = lo; i < hi; ++i) {
        int h = hist[i];      // read BEFORE aliased write
        cursor[i] = run;
        run += h;
    }
}

__global__ void scatter_kernel(const int* __restrict__ srcI, const int* __restrict__ dstI,
                               int* __restrict__ cursor,
                               int* __restrict__ se2, int* __restrict__ de2) {
    int i = blockIdx.x * blockDim.x + threadIdx.x;
    if (i < NE) {
        int d = dstI[i];
        int p = atomicAdd(&cursor[d], 1);
        se2[p] = srcI[i];
        de2[p] = d;
    }
}

// ---------------- weight prep ----------------
// WcT [512][C]: rows 0..255 = (w1t-w1b)^T, 256..511 = w1b^T.  w2T [256][256] = w2^T.
__global__ void prep_weights(const float* __restrict__ w1, const float* __restrict__ w2, int C,
                             _Float16* __restrict__ WcT, _Float16* __restrict__ w2T) {
    int total1 = 512 * C;
    int total = total1 + 256 * 256;
    for (int i = blockIdx.x * blockDim.x + threadIdx.x; i < total; i += gridDim.x * blockDim.x) {
        if (i < total1) {
            int n = i / C, k = i - n * C;
            float v = (n < 256) ? (w1[k * 256 + n] - w1[(C + k) * 256 + n])
                                : w1[(C + k) * 256 + (n - 256)];
            WcT[n * C + k] = (_Float16)v;
        } else {
            int j = i - total1;
            int n = j >> 8, k = j & 255;
            w2T[n * 256 + k] = (_Float16)w2[k * 256 + n];
        }
    }
}

// ---------------- node GEMM: [A | B] = x @ [Wc_A | Wc_B]; both f16 (A gets +b1) --------
// grid (157,4): wave = M64 x N32 -> 628 blocks, ~10 waves/CU for latency hiding.
// Reads f32 activations directly (x0 or y), converts inline; rows clamped (pad never used).
template <int C>
__global__ __launch_bounds__(256, 4) void node_gemm(
    const float* __restrict__ xf, const _Float16* __restrict__ WT,
    const float* __restrict__ b1, _Float16* __restrict__ Afh, _Float16* __restrict__ Bh) {
    const int wave = threadIdx.x >> 6, lane = threadIdx.x & 63;
    const int lrow = lane & 15, lk = (lane >> 4) * 8;
    const int r0 = blockIdx.x * 64;
    const int c0 = blockIdx.y * 128 + wave * 32;

    f32x4 acc[4][2] = {};
#pragma unroll
    for (int kk = 0; kk < C; kk += 32) {
        f16x8 ah[4];
#pragma unroll
        for (int m = 0; m < 4; ++m) {
            int rc = r0 + m * 16 + lrow;
            if (rc > NN - 1) rc = NN - 1;
            const float* xp = xf + (size_t)rc * C + kk + lk;
            const float4 v0 = *(const float4*)(xp);
            const float4 v1 = *(const float4*)(xp + 4);
            f16x8 a;
            a[0] = (_Float16)v0.x; a[1] = (_Float16)v0.y;
            a[2] = (_Float16)v0.z; a[3] = (_Float16)v0.w;
            a[4] = (_Float16)v1.x; a[5] = (_Float16)v1.y;
            a[6] = (_Float16)v1.z; a[7] = (_Float16)v1.w;
            ah[m] = a;
        }
#pragma unroll
        for (int t = 0; t < 2; ++t) {
            f16x8 bh = *(const f16x8*)(WT + (size_t)(c0 + t * 16 + lrow) * C + kk + lk);
#pragma unroll
            for (int m = 0; m < 4; ++m)
                acc[m][t] = __builtin_amdgcn_mfma_f32_16x16x32_f16(ah[m], bh, acc[m][t], 0, 0, 0);
        }
    }
    if (blockIdx.y < 2) {  // A half: +bias (f32), store f16
#pragma unroll
        for (int t = 0; t < 2; ++t) {
            const int col = c0 + t * 16 + lrow;
            const float bias = b1[col];
#pragma unroll
            for (int m = 0; m < 4; ++m)
#pragma unroll
                for (int j = 0; j < 4; ++j) {
                    const int row = r0 + m * 16 + (lane >> 4) * 4 + j;
                    Afh[(size_t)row * 256 + col] = (_Float16)(acc[m][t][j] + bias);
                }
        }
    } else {  // B half: f16
#pragma unroll
        for (int t = 0; t < 2; ++t) {
            const int col = c0 - 256 + t * 16 + lrow;
#pragma unroll
            for (int m = 0; m < 4; ++m)
#pragma unroll
                for (int j = 0; j < 4; ++j) {
                    const int row = r0 + m * 16 + (lane >> 4) * 4 + j;
                    Bh[(size_t)row * 256 + col] = (_Float16)acc[m][t][j];
                }
        }
    }
}

// ---------------- fused edge kernel: 5-tile pipeline, bh streamed from L2 ----------------
__global__ __launch_bounds__(512, 2) void edge_gemm(
    const _Float16* __restrict__ Afh, const _Float16* __restrict__ Bh,
    const int* __restrict__ se2, const int* __restrict__ de2,
    const _Float16* __restrict__ w2T,
    const float* __restrict__ b2, float* __restrict__ y) {
    __shared__ _Float16 hh[2 * EB * 256];  // 64 KB double buffer, XOR-swizzled
    const int tid = threadIdx.x;
    const int wave = tid >> 6, lane = tid & 63;
    const int lrow = lane & 15, lk = (lane >> 4) * 8;

    // XCD-chunked bijective swizzle over 500 blocks (= 8*62 + 4)
    const int orig = blockIdx.x;
    const int xcd = orig & 7, pos = orig >> 3;
    const int qq = NBLK >> 3, rr = NBLK & 7;  // 62, 4
    const int bid = (xcd < rr ? xcd * (qq + 1) : rr * (qq + 1) + (xcd - rr) * qq) + pos;
    const int t0 = bid * TPB;  // first tile

    const _Float16* wbase = w2T + (size_t)(wave * 32 + lrow) * 256 + lk;

    f16x4 av[8], bv[8];

    auto stage_issue = [&](int tile) {
        int se[8], de[8];
#pragma unroll
        for (int i = 0; i < 8; ++i) {
            const int e = tile * EB + wave * 8 + i;
            se[i] = se2[e];
            de[i] = de2[e];
        }
#pragma unroll
        for (int i = 0; i < 8; ++i) {
            bv[i] = *(const f16x4*)(Bh + (size_t)se[i] * 256 + lane * 4);
            av[i] = *(const f16x4*)(Afh + (size_t)de[i] * 256 + lane * 4);
        }
    };
    auto stage_write = [&](int buf) {
#pragma unroll
        for (int i = 0; i < 8; ++i) {
            const int el = wave * 8 + i;  // block-local edge 0..63
            const int row = ((el >> 2) & 3) * 16 + (el >> 4) * 4 + (el & 3);
            f16x4 h = av[i] + bv[i];
#pragma unroll
            for (int k = 0; k < 4; ++k) h[k] = h[k] > (_Float16)0.f ? h[k] : (_Float16)0.f;
            *(f16x4*)(&hh[buf * (EB * 256) + ((row * 256 + lane * 4) ^ ((row & 7) << 3))]) = h;
        }
    };

    // prologue: stage tile 0 into buf 0
    stage_issue(t0);
    stage_write(0);
    __syncthreads();

    for (int tt = 0; tt < TPB; ++tt) {
        const int tile = t0 + tt;
        const int hbase = (tt & 1) * (EB * 256);

        if (tt + 1 < TPB) stage_issue(tile + 1);  // gathers fly during GEMM+epilogue

        // ---- GEMM: M=64 (4 tiles) x N=32 (2 tiles), K=256; bh streams from L2 ----
        f32x4 acc[4][2] = {};
#pragma unroll
        for (int q = 0; q < 8; ++q) {
            f16x8 bh0 = *(const f16x8*)(wbase + q * 32);
            f16x8 bh1 = *(const f16x8*)(wbase + 16 * 256 + q * 32);
            f16x8 ah[4];
#pragma unroll
            for (int m = 0; m < 4; ++m) {
                const int row = m * 16 + lrow;
                const int idx = (row * 256 + q * 32 + lk) ^ ((row & 7) << 3);
                ah[m] = *(const f16x8*)(&hh[hbase + idx]);
            }
#pragma unroll
            for (int m = 0; m < 4; ++m) {
                acc[m][0] = __builtin_amdgcn_mfma_f32_16x16x32_f16(ah[m], bh0, acc[m][0], 0, 0, 0);
                acc[m][1] = __builtin_amdgcn_mfma_f32_16x16x32_f16(ah[m], bh1, acc[m][1], 0, 0, 0);
            }
        }

        // ---- epilogue: lane quarter g holds edges tile*64 + g*16..+15 (consecutive) ----
        {
            const int g = lane >> 4;
            const int e0 = tile * EB;
            int d[16];
#pragma unroll
            for (int k = 0; k < 16; ++k) d[k] = de2[e0 + g * 16 + k];
#pragma unroll
            for (int t = 0; t < 2; ++t) {
                const int col = wave * 32 + t * 16 + lrow;
                const float bias = b2[col];  // constant per col: apply AFTER segment max
                float run = acc[0][t][0];
                int dp = d[0];
#pragma unroll
                for (int k = 1; k < 16; ++k) {
                    const float v = acc[k >> 2][t][k & 3];
                    if (d[k] == dp) {
                        run = fmaxf(run, v);
                    } else {
                        const float o = run + bias;
                        if (o > 0.f) atomicMax((int*)(y + (size_t)dp * 256 + col), __float_as_int(o));
                        run = v;
                        dp = d[k];
                    }
                }
                const float o = run + bias;
                if (o > 0.f) atomicMax((int*)(y + (size_t)dp * 256 + col), __float_as_int(o));
            }
        }

        if (tt + 1 < TPB) stage_write((tt + 1) & 1);
        __syncthreads();
    }
}

// ---------------- per-graph mean+max pool (4 row-slices per block) ----------------
__global__ void pool_kernel(const float* __restrict__ y, const int* __restrict__ batch,
                            float* __restrict__ pooled) {
    const int g = blockIdx.x;
    __shared__ int slo, shi;
    __shared__ float ssum[4][256];
    __shared__ float smax[4][256];
    const int c = threadIdx.x, ry = threadIdx.y;
    if (c == 0 && ry == 0) {
        int lo = 0, hi = NN;
        while (lo < hi) { int m = (lo + hi) >> 1; if (batch[m] < g) lo = m + 1; else hi = m; }
        slo = lo;
        int lo2 = lo, hi2 = NN;
        while (lo2 < hi2) { int m = (lo2 + hi2) >> 1; if (batch[m] < g + 1) lo2 = m + 1; else hi2 = m; }
        shi = lo2;
    }
    __syncthreads();
    const int lo = slo, hi = shi;
    float s = 0.f, mx = 0.f;  // y >= 0 -> 0 safe identity
    for (int n = lo + ry; n < hi; n += 4) {
        const float v = y[(size_t)n * 256 + c];
        s += v;
        mx = fmaxf(mx, v);
    }
    ssum[ry][c] = s;
    smax[ry][c] = mx;
    __syncthreads();
    if (ry == 0) {
        const float st = (ssum[0][c] + ssum[1][c]) + (ssum[2][c] + ssum[3][c]);
        const float mt = fmaxf(fmaxf(smax[0][c], smax[1][c]), fmaxf(smax[2][c], smax[3][c]));
        const int cnt = hi - lo;
        pooled[g * 512 + c] = cnt ? st / (float)cnt : 0.f;
        pooled[g * 512 + 256 + c] = cnt ? mt : 0.f;
    }
}

// ---------------- classifier MLP ----------------
__global__ void classifier(const float* __restrict__ pooled,
                           const float* __restrict__ w1, const float* __restrict__ b1,
                           const float* __restrict__ w2, const float* __restrict__ b2,
                           const float* __restrict__ w3, const float* __restrict__ b3,
                           float* __restrict__ out) {
    const int g = blockIdx.x;
    __shared__ float ph[512];
    __shared__ float o1[256];
    __shared__ float o2[64];
    const int t = threadIdx.x;  // 256 threads
    ph[t] = pooled[g * 512 + t];
    ph[t + 256] = pooled[g * 512 + 256 + t];
    __syncthreads();
    float s = 0.f;
    for (int k = 0; k < 512; ++k) s += ph[k] * w1[k * 256 + t];
    o1[t] = fmaxf(s + b1[t], 0.f);
    __syncthreads();
    if (t < 64) {
        float s2 = 0.f;
        for (int k = 0; k < 256; ++k) s2 += o1[k] * w2[k * 64 + t];
        o2[t] = fmaxf(s2 + b2[t], 0.f);
    }
    __syncthreads();
    if (t < 64) {
        float v = o2[t] * w3[t];
        for (int off = 32; off; off >>= 1) v += __shfl_down(v, off);
        if (t == 0) out[g] = v + b3[0];
    }
}

extern "C" void kernel_launch(void* const* d_in, const int* in_sizes, int n_in,
                              void* d_out, int out_size, void* d_ws, size_t ws_size,
                              hipStream_t stream) {
    (void)in_sizes; (void)n_in; (void)out_size; (void)ws_size;
    const float* x0 = (const float*)d_in[0];
    const int* eidx = (const int*)d_in[1];
    const int* batch = (const int*)d_in[2];
    const int* srcI = eidx;            // edge_index[0] = src
    const int* dstI = eidx + NE;       // edge_index[1] = dst

    char* ws = (char*)d_ws;
    size_t off = 0;
    auto alloc = [&](size_t bytes) -> void* {
        void* p = ws + off;
        off += (bytes + 255) & ~(size_t)255;
        return p;
    };
    _Float16* Afh = (_Float16*)alloc((size_t)NP * 256 * 2);
    _Float16* Bh  = (_Float16*)alloc((size_t)NP * 256 * 2);
    float* y  = (float*)alloc((size_t)NP * 256 * 4);
    _Float16* WcT = (_Float16*)alloc(512 * 256 * 2);
    _Float16* w2T = (_Float16*)alloc(256 * 256 * 2);
    float* pooled = (float*)alloc(64 * 512 * 4);
    int* hist = (int*)alloc(NN * 4);
    int* se2 = (int*)alloc(NE * 4);
    int* de2 = (int*)alloc(NE * 4);

    const float* lw[3][4] = {
        {(const float*)d_in[3],  (const float*)d_in[4],  (const float*)d_in[5],  (const float*)d_in[6]},
        {(const float*)d_in[7],  (const float*)d_in[8],  (const float*)d_in[9],  (const float*)d_in[10]},
        {(const float*)d_in[11], (const float*)d_in[12], (const float*)d_in[13], (const float*)d_in[14]},
    };

    // sort edges by dst (once, reused all layers)
    hipMemsetAsync(hist, 0, NN * 4, stream);
    hist_kernel<<<dim3((NE + 255) / 256), dim3(256), 0, stream>>>(dstI, hist);
    scan_kernel<<<dim3(1), dim3(256), 0, stream>>>(hist, hist);  // in-place exclusive scan
    scatter_kernel<<<dim3((NE + 255) / 256), dim3(256), 0, stream>>>(srcI, dstI, hist, se2, de2);

    for (int l = 0; l < 3; ++l) {
        const int C = (l == 0) ? 128 : 256;
        prep_weights<<<dim3(256), dim3(256), 0, stream>>>(lw[l][0], lw[l][2], C, WcT, w2T);
        if (C == 128)
            node_gemm<128><<<dim3(NP / 64, 4), dim3(256), 0, stream>>>(x0, WcT, lw[l][1], Afh, Bh);
        else
            node_gemm<256><<<dim3(NP / 64, 4), dim3(256), 0, stream>>>(y, WcT, lw[l][1], Afh, Bh);
        hipMemsetAsync(y, 0, (size_t)NP * 256 * 4, stream);
        edge_gemm<<<dim3(NBLK), dim3(512), 0, stream>>>(Afh, Bh, se2, de2, w2T, lw[l][3], y);
    }

    pool_kernel<<<dim3(NG), dim3(256, 4), 0, stream>>>(y, batch, pooled);
    classifier<<<dim3(NG), dim3(256), 0, stream>>>(pooled,
        (const float*)d_in[15], (const float*)d_in[16],
        (const float*)d_in[17], (const float*)d_in[18],
        (const float*)d_in[19], (const float*)d_in[20], (float*)d_out);
}

// Round 15
// 356.308 us; speedup vs baseline: 1.5023x; 1.0305x over previous
//
#include <hip/hip_runtime.h>

// PocketGNN on MI355X — round 11.
// - EdgeConv first matmul on nodes: A = x@(w1t-w1b)+b1 (f16), B = x@w1b (f16)
// - edge_gemm: 512 thr / 8 waves, wave = M64 x N32, EB=64, 5 tiles/block,
//   double-buffered LDS, (512,2) -> 128-reg budget, no spill (R10: VGPR 116).
//   NEW: raw lgkm-only barrier (asm "s_waitcnt lgkmcnt(0); s_barrier") -- LDS
//   ordering preserved, but the ~32 in-flight atomicMax per lane are NOT drained
//   at the barrier; epilogue(t) moved AFTER the barrier so its atomics complete
//   under GEMM(t+1). NEW: full (row&15)<<3 XOR swizzle -> conflict-free b128.
// - Edges dst-sorted; permuted LDS rows so each lane quarter's 16 acc values are
//   16 consecutive sorted edges -> register segment-max, merged atomics.
// - XCD-chunked bijective block swizzle (grid 500 = 8*62+4).
// - relu(segment_max) == atomicMax(int) of positives into zero-init y.

#define NN 10000
#define NE 160000
#define NG 64
#define NP 10048  // nodes padded to 64
#define EB 64     // edges per tile
#define TPB 5     // tiles per block
#define NBLK 500  // 2500 tiles / 5

typedef __attribute__((ext_vector_type(8))) _Float16 f16x8;
typedef __attribute__((ext_vector_type(4))) _Float16 f16x4;
typedef __attribute__((ext_vector_type(4))) float f32x4;

// lgkm-only barrier: orders LDS across waves, leaves vmem (atomics/gathers) in flight
#define LGKM_BARRIER() asm volatile("s_waitcnt lgkmcnt(0)\n\ts_barrier" ::: "memory")

// ---------------- edge sort by dst (counting sort) ----------------
__global__ void hist_kernel(const int* __restrict__ dstI, int* __restrict__ hist) {
    int i = blockIdx.x * blockDim.x + threadIdx.x;
    if (i < NE) atomicAdd(&hist[dstI[i]], 1);
}

// in-place safe: cursor may alias hist
__global__ void scan_kernel(const int* __restrict__ hist, int* __restrict__ cursor) {
    __shared__ int sums[256];
    const int t = threadIdx.x;
    const int per = (NN + 255) / 256;  // 40
    const int lo = t * per, hi = (lo + per < NN) ? lo + per : NN;
    int s = 0;
    for (int i = lo; i < hi; ++i) s += hist[i];
    sums[t] = s;
    __syncthreads();
    for (int ofs = 1; ofs < 256; ofs <<= 1) {
        int add = (t >= ofs) ? sums[t - ofs] : 0;
        __syncthreads();
        sums[t] += add;
        __syncthreads();
    }
    int run = sums[t] - s;  // exclusive prefix
    for (int i = lo; i < hi; ++i) {
        int h = hist[i];      // read BEFORE aliased write
        cursor[i] = run;
        run += h;
    }
}

__global__ void scatter_kernel(const int* __restrict__ srcI, const int* __restrict__ dstI,
                               int* __restrict__ cursor,
                               int* __restrict__ se2, int* __restrict__ de2) {
    int i = blockIdx.x * blockDim.x + threadIdx.x;
    if (i < NE) {
        int d = dstI[i];
        int p = atomicAdd(&cursor[d], 1);
        se2[p] = srcI[i];
        de2[p] = d;
    }
}

// ---------------- weight prep ----------------
// WcT [512][C]: rows 0..255 = (w1t-w1b)^T, 256..511 = w1b^T.  w2T [256][256] = w2^T.
__global__ void prep_weights(const float* __restrict__ w1, const float* __restrict__ w2, int C,
                             _Float16* __restrict__ WcT, _Float16* __restrict__ w2T) {
    int total1 = 512 * C;
    int total = total1 + 256 * 256;
    for (int i = blockIdx.x * blockDim.x + threadIdx.x; i < total; i += gridDim.x * blockDim.x) {
        if (i < total1) {
            int n = i / C, k = i - n * C;
            float v = (n < 256) ? (w1[k * 256 + n] - w1[(C + k) * 256 + n])
                                : w1[(C + k) * 256 + (n - 256)];
            WcT[n * C + k] = (_Float16)v;
        } else {
            int j = i - total1;
            int n = j >> 8, k = j & 255;
            w2T[n * 256 + k] = (_Float16)w2[k * 256 + n];
        }
    }
}

// ---------------- node GEMM: [A | B] = x @ [Wc_A | Wc_B]; both f16 (A gets +b1) --------
// grid (157,2): wave = M64 x N64 (acc[4][4]) -> x re-read only 2x (R7's (157,4) was 4x).
// Reads f32 activations directly (x0 or y), converts inline; rows clamped (pad never used).
template <int C>
__global__ __launch_bounds__(256, 2) void node_gemm(
    const float* __restrict__ xf, const _Float16* __restrict__ WT,
    const float* __restrict__ b1, _Float16* __restrict__ Afh, _Float16* __restrict__ Bh) {
    const int wave = threadIdx.x >> 6, lane = threadIdx.x & 63;
    const int lrow = lane & 15, lk = (lane >> 4) * 8;
    const int r0 = blockIdx.x * 64;
    const int c0 = blockIdx.y * 256 + wave * 64;

    f32x4 acc[4][4] = {};
#pragma unroll
    for (int kk = 0; kk < C; kk += 32) {
        f16x8 ah[4];
#pragma unroll
        for (int m = 0; m < 4; ++m) {
            int rc = r0 + m * 16 + lrow;
            if (rc > NN - 1) rc = NN - 1;
            const float* xp = xf + (size_t)rc * C + kk + lk;
            const float4 v0 = *(const float4*)(xp);
            const float4 v1 = *(const float4*)(xp + 4);
            f16x8 a;
            a[0] = (_Float16)v0.x; a[1] = (_Float16)v0.y;
            a[2] = (_Float16)v0.z; a[3] = (_Float16)v0.w;
            a[4] = (_Float16)v1.x; a[5] = (_Float16)v1.y;
            a[6] = (_Float16)v1.z; a[7] = (_Float16)v1.w;
            ah[m] = a;
        }
#pragma unroll
        for (int t = 0; t < 4; ++t) {
            f16x8 bh = *(const f16x8*)(WT + (size_t)(c0 + t * 16 + lrow) * C + kk + lk);
#pragma unroll
            for (int m = 0; m < 4; ++m)
                acc[m][t] = __builtin_amdgcn_mfma_f32_16x16x32_f16(ah[m], bh, acc[m][t], 0, 0, 0);
        }
    }
    if (blockIdx.y == 0) {  // A half: +bias (f32), store f16
#pragma unroll
        for (int t = 0; t < 4; ++t) {
            const int col = c0 + t * 16 + lrow;
            const float bias = b1[col];
#pragma unroll
            for (int m = 0; m < 4; ++m)
#pragma unroll
                for (int j = 0; j < 4; ++j) {
                    const int row = r0 + m * 16 + (lane >> 4) * 4 + j;
                    Afh[(size_t)row * 256 + col] = (_Float16)(acc[m][t][j] + bias);
                }
        }
    } else {  // B half: f16
#pragma unroll
        for (int t = 0; t < 4; ++t) {
            const int col = c0 - 256 + t * 16 + lrow;
#pragma unroll
            for (int m = 0; m < 4; ++m)
#pragma unroll
                for (int j = 0; j < 4; ++j) {
                    const int row = r0 + m * 16 + (lane >> 4) * 4 + j;
                    Bh[(size_t)row * 256 + col] = (_Float16)acc[m][t][j];
                }
        }
    }
}

// ---------------- fused edge kernel: 5-tile pipeline, deferred-atomic epilogue --------
__global__ __launch_bounds__(512, 2) void edge_gemm(
    const _Float16* __restrict__ Afh, const _Float16* __restrict__ Bh,
    const int* __restrict__ se2, const int* __restrict__ de2,
    const _Float16* __restrict__ w2T,
    const float* __restrict__ b2, float* __restrict__ y) {
    __shared__ _Float16 hh[2 * EB * 256];  // 64 KB double buffer, XOR-swizzled
    const int tid = threadIdx.x;
    const int wave = tid >> 6, lane = tid & 63;
    const int lrow = lane & 15, lk = (lane >> 4) * 8;

    // XCD-chunked bijective swizzle over 500 blocks (= 8*62 + 4)
    const int orig = blockIdx.x;
    const int xcd = orig & 7, pos = orig >> 3;
    const int qq = NBLK >> 3, rr = NBLK & 7;  // 62, 4
    const int bid = (xcd < rr ? xcd * (qq + 1) : rr * (qq + 1) + (xcd - rr) * qq) + pos;
    const int t0 = bid * TPB;  // first tile

    const _Float16* wbase = w2T + (size_t)(wave * 32 + lrow) * 256 + lk;

    f16x4 av[8], bv[8];

    auto stage_issue = [&](int tile) {
        int se[8], de[8];
#pragma unroll
        for (int i = 0; i < 8; ++i) {
            const int e = tile * EB + wave * 8 + i;
            se[i] = se2[e];
            de[i] = de2[e];
        }
#pragma unroll
        for (int i = 0; i < 8; ++i) {
            bv[i] = *(const f16x4*)(Bh + (size_t)se[i] * 256 + lane * 4);
            av[i] = *(const f16x4*)(Afh + (size_t)de[i] * 256 + lane * 4);
        }
    };
    auto stage_write = [&](int buf) {
#pragma unroll
        for (int i = 0; i < 8; ++i) {
            const int el = wave * 8 + i;  // block-local edge 0..63
            const int row = ((el >> 2) & 3) * 16 + (el >> 4) * 4 + (el & 3);
            f16x4 h = av[i] + bv[i];
#pragma unroll
            for (int k = 0; k < 4; ++k) h[k] = h[k] > (_Float16)0.f ? h[k] : (_Float16)0.f;
            *(f16x4*)(&hh[buf * (EB * 256) + ((row * 256 + lane * 4) ^ ((row & 15) << 3))]) = h;
        }
    };

    // prologue: stage tile 0 into buf 0
    stage_issue(t0);
    stage_write(0);
    LGKM_BARRIER();

    for (int tt = 0; tt < TPB; ++tt) {
        const int tile = t0 + tt;
        const int hbase = (tt & 1) * (EB * 256);

        if (tt + 1 < TPB) stage_issue(tile + 1);  // gathers fly during GEMM

        // ---- GEMM: M=64 (4 tiles) x N=32 (2 tiles), K=256; bh streams from L2 ----
        f32x4 acc[4][2] = {};
#pragma unroll
        for (int q = 0; q < 8; ++q) {
            f16x8 bh0 = *(const f16x8*)(wbase + q * 32);
            f16x8 bh1 = *(const f16x8*)(wbase + 16 * 256 + q * 32);
            f16x8 ah[4];
#pragma unroll
            for (int m = 0; m < 4; ++m) {
                const int row = m * 16 + lrow;
                const int idx = (row * 256 + q * 32 + lk) ^ ((row & 15) << 3);
                ah[m] = *(const f16x8*)(&hh[hbase + idx]);
            }
#pragma unroll
            for (int m = 0; m < 4; ++m) {
                acc[m][0] = __builtin_amdgcn_mfma_f32_16x16x32_f16(ah[m], bh0, acc[m][0], 0, 0, 0);
                acc[m][1] = __builtin_amdgcn_mfma_f32_16x16x32_f16(ah[m], bh1, acc[m][1], 0, 0, 0);
            }
        }

        if (tt + 1 < TPB) stage_write((tt + 1) & 1);
        LGKM_BARRIER();  // LDS ordered; atomics/vmem stay in flight

        // ---- epilogue AFTER barrier: atomics issue here, complete under next GEMM ----
        {
            const int g = lane >> 4;
            const int e0 = tile * EB;
            int d[16];
#pragma unroll
            for (int k = 0; k < 16; ++k) d[k] = de2[e0 + g * 16 + k];
#pragma unroll
            for (int t = 0; t < 2; ++t) {
                const int col = wave * 32 + t * 16 + lrow;
                const float bias = b2[col];  // constant per col: apply AFTER segment max
                float run = acc[0][t][0];
                int dp = d[0];
#pragma unroll
                for (int k = 1; k < 16; ++k) {
                    const float v = acc[k >> 2][t][k & 3];
                    if (d[k] == dp) {
                        run = fmaxf(run, v);
                    } else {
                        const float o = run + bias;
                        if (o > 0.f) atomicMax((int*)(y + (size_t)dp * 256 + col), __float_as_int(o));
                        run = v;
                        dp = d[k];
                    }
                }
                const float o = run + bias;
                if (o > 0.f) atomicMax((int*)(y + (size_t)dp * 256 + col), __float_as_int(o));
            }
        }
    }
}

// ---------------- per-graph mean+max pool (4 row-slices per block) ----------------
__global__ void pool_kernel(const float* __restrict__ y, const int* __restrict__ batch,
                            float* __restrict__ pooled) {
    const int g = blockIdx.x;
    __shared__ int slo, shi;
    __shared__ float ssum[4][256];
    __shared__ float smax[4][256];
    const int c = threadIdx.x, ry = threadIdx.y;
    if (c == 0 && ry == 0) {
        int lo = 0, hi = NN;
        while (lo < hi) { int m = (lo + hi) >> 1; if (batch[m] < g) lo = m + 1; else hi = m; }
        slo = lo;
        int lo2 = lo, hi2 = NN;
        while (lo2 < hi2) { int m = (lo2 + hi2) >> 1; if (batch[m] < g + 1) lo2 = m + 1; else hi2 = m; }
        shi = lo2;
    }
    __syncthreads();
    const int lo = slo, hi = shi;
    float s = 0.f, mx = 0.f;  // y >= 0 -> 0 safe identity
    for (int n = lo + ry; n < hi; n += 4) {
        const float v = y[(size_t)n * 256 + c];
        s += v;
        mx = fmaxf(mx, v);
    }
    ssum[ry][c] = s;
    smax[ry][c] = mx;
    __syncthreads();
    if (ry == 0) {
        const float st = (ssum[0][c] + ssum[1][c]) + (ssum[2][c] + ssum[3][c]);
        const float mt = fmaxf(fmaxf(smax[0][c], smax[1][c]), fmaxf(smax[2][c], smax[3][c]));
        const int cnt = hi - lo;
        pooled[g * 512 + c] = cnt ? st / (float)cnt : 0.f;
        pooled[g * 512 + 256 + c] = cnt ? mt : 0.f;
    }
}

// ---------------- classifier MLP ----------------
__global__ void classifier(const float* __restrict__ pooled,
                           const float* __restrict__ w1, const float* __restrict__ b1,
                           const float* __restrict__ w2, const float* __restrict__ b2,
                           const float* __restrict__ w3, const float* __restrict__ b3,
                           float* __restrict__ out) {
    const int g = blockIdx.x;
    __shared__ float ph[512];
    __shared__ float o1[256];
    __shared__ float o2[64];
    const int t = threadIdx.x;  // 256 threads
    ph[t] = pooled[g * 512 + t];
    ph[t + 256] = pooled[g * 512 + 256 + t];
    __syncthreads();
    float s = 0.f;
    for (int k = 0; k < 512; ++k) s += ph[k] * w1[k * 256 + t];
    o1[t] = fmaxf(s + b1[t], 0.f);
    __syncthreads();
    if (t < 64) {
        float s2 = 0.f;
        for (int k = 0; k < 256; ++k) s2 += o1[k] * w2[k * 64 + t];
        o2[t] = fmaxf(s2 + b2[t], 0.f);
    }
    __syncthreads();
    if (t < 64) {
        float v = o2[t] * w3[t];
        for (int off = 32; off; off >>= 1) v += __shfl_down(v, off);
        if (t == 0) out[g] = v + b3[0];
    }
}

extern "C" void kernel_launch(void* const* d_in, const int* in_sizes, int n_in,
                              void* d_out, int out_size, void* d_ws, size_t ws_size,
                              hipStream_t stream) {
    (void)in_sizes; (void)n_in; (void)out_size; (void)ws_size;
    const float* x0 = (const float*)d_in[0];
    const int* eidx = (const int*)d_in[1];
    const int* batch = (const int*)d_in[2];
    const int* srcI = eidx;            // edge_index[0] = src
    const int* dstI = eidx + NE;       // edge_index[1] = dst

    char* ws = (char*)d_ws;
    size_t off = 0;
    auto alloc = [&](size_t bytes) -> void* {
        void* p = ws + off;
        off += (bytes + 255) & ~(size_t)255;
        return p;
    };
    _Float16* Afh = (_Float16*)alloc((size_t)NP * 256 * 2);
    _Float16* Bh  = (_Float16*)alloc((size_t)NP * 256 * 2);
    float* y  = (float*)alloc((size_t)NP * 256 * 4);
    _Float16* WcT = (_Float16*)alloc(512 * 256 * 2);
    _Float16* w2T = (_Float16*)alloc(256 * 256 * 2);
    float* pooled = (float*)alloc(64 * 512 * 4);
    int* hist = (int*)alloc(NN * 4);
    int* se2 = (int*)alloc(NE * 4);
    int* de2 = (int*)alloc(NE * 4);

    const float* lw[3][4] = {
        {(const float*)d_in[3],  (const float*)d_in[4],  (const float*)d_in[5],  (const float*)d_in[6]},
        {(const float*)d_in[7],  (const float*)d_in[8],  (const float*)d_in[9],  (const float*)d_in[10]},
        {(const float*)d_in[11], (const float*)d_in[12], (const float*)d_in[13], (const float*)d_in[14]},
    };

    // sort edges by dst (once, reused all layers)
    hipMemsetAsync(hist, 0, NN * 4, stream);
    hist_kernel<<<dim3((NE + 255) / 256), dim3(256), 0, stream>>>(dstI, hist);
    scan_kernel<<<dim3(1), dim3(256), 0, stream>>>(hist, hist);  // in-place exclusive scan
    scatter_kernel<<<dim3((NE + 255) / 256), dim3(256), 0, stream>>>(srcI, dstI, hist, se2, de2);

    for (int l = 0; l < 3; ++l) {
        const int C = (l == 0) ? 128 : 256;
        prep_weights<<<dim3(256), dim3(256), 0, stream>>>(lw[l][0], lw[l][2], C, WcT, w2T);
        if (C == 128)
            node_gemm<128><<<dim3(NP / 64, 2), dim3(256), 0, stream>>>(x0, WcT, lw[l][1], Afh, Bh);
        else
            node_gemm<256><<<dim3(NP / 64, 2), dim3(256), 0, stream>>>(y, WcT, lw[l][1], Afh, Bh);
        hipMemsetAsync(y, 0, (size_t)NP * 256 * 4, stream);
        edge_gemm<<<dim3(NBLK), dim3(512), 0, stream>>>(Afh, Bh, se2, de2, w2T, lw[l][3], y);
    }

    pool_kernel<<<dim3(NG), dim3(256, 4), 0, stream>>>(y, batch, pooled);
    classifier<<<dim3(NG), dim3(256), 0, stream>>>(pooled,
        (const float*)d_in[15], (const float*)d_in[16],
        (const float*)d_in[17], (const float*)d_in[18],
        (const float*)d_in[19], (const float*)d_in[20], (float*)d_out);
}